// Round 13
// baseline (149.336 us; speedup 1.0000x reference)
//
#include <hip/hip_runtime.h>
#include <hip/hip_bf16.h>
#include <math.h>

// Problem constants (reference: B=2048, CI=32, CO=32, A=16, ITER_NUM=5)
constexpr int CI = 32;
constexpr int CO = 32;
constexpr float INV_N   = 1.0f / 65536.0f;
constexpr float INV_NM1 = 1.0f / 65535.0f;

// DIAGNOSTIC ROUND: run each streaming kernel's body 3x so both rise above
// the ~75us harness poison-fills and appear in rocprof's top-5. Exactness:
// k_stats accumulates 3x (P'=3P, S'=3S) and k_ns rescales by exactly 1/3;
// k_apply's extra passes write identical values (idempotent).
constexpr int DUP_STATS = 3;
constexpr int REP_APPLY = 3;

constexpr int NCHUNK = 32;                 // stats chunks per capsule
constexpr int PART_STRIDE = 272;           // 16 rows * 17 (16 cols + 1 sum)

constexpr int WS_PART = 0;
constexpr int WS_WG   = CI * NCHUNK * PART_STRIDE;   // 278528
constexpr int WS_C0   = WS_WG + CI * 256;

constexpr int BSTRIDE = 16384;             // floats per batch (64 KB)

using f32x4  = __attribute__((ext_vector_type(4))) float;
using bf16x8 = __attribute__((ext_vector_type(8))) short;

// ---------------------------------------------------------------------------
// Kernel 1 (MFMA Gram): R10 body exactly, wrapped in DUP_STATS passes.
// Grid: 32 ci * 32 chunks = 1024 blocks of 256 threads (4 blocks/CU).
// ---------------------------------------------------------------------------
__global__ __launch_bounds__(256) void k_stats(const float* __restrict__ x,
                                               float* __restrict__ ws) {
    const int ci    = blockIdx.x & 31;
    const int chunk = blockIdx.x >> 5;          // 0..31
    const int tid   = threadIdx.x;
    const int lane  = tid & 63;
    const int wv    = tid >> 6;
    const int m     = lane & 15;                // row/col index this lane owns
    const int g     = lane >> 4;                // k-group (co = g*8 + j)

    f32x4 acc = {0.0f, 0.0f, 0.0f, 0.0f};
    float sacc = 0.0f;

    const int b0 = chunk * 64 + wv * 16;
    const float* const pbase =
        x + ((size_t)(b0 * 32 + ci) * 32 + g * 8) * 16 + m;

    float bufA[8], bufB[8];

    auto ld = [&](float (&d)[8], const float* q) {
#pragma unroll
        for (int j = 0; j < 8; ++j) d[j] = q[j * 16];
    };
    auto step = [&](float (&buf)[8]) {
        union { bf16x8 v; unsigned short h[8]; } fu;
#pragma unroll
        for (int j = 0; j < 8; ++j) {
            sacc += buf[j];                     // exact fp32 column sum
            fu.h[j] = __bfloat16_as_ushort(__float2bfloat16(buf[j]));
        }
        acc = __builtin_amdgcn_mfma_f32_16x16x32_bf16(fu.v, fu.v, acc, 0, 0, 0);
    };

    for (int pass = 0; pass < DUP_STATS; ++pass) {
        const float* p = pbase;
        ld(bufA, p);
        ld(bufB, p + BSTRIDE);
        p += 2 * BSTRIDE;
#pragma unroll
        for (int rr = 0; rr < 8; ++rr) {
            step(bufA);
            if (rr < 7) { ld(bufA, p); p += BSTRIDE; }
            step(bufB);
            if (rr < 7) { ld(bufB, p); p += BSTRIDE; }
        }
    }

    // S[m]: sum sacc across the 4 k-groups (lanes 16 apart).
    sacc += __shfl_xor(sacc, 16, 64);
    sacc += __shfl_xor(sacc, 32, 64);

    // C/D layout (m89-verified): lane holds P[row=g*4+q][col=m], q=0..3.
    __shared__ float red[4][272];
#pragma unroll
    for (int q = 0; q < 4; ++q)
        red[wv][(g * 4 + q) * 17 + m] = acc[q];
    if (g == 0) red[wv][m * 17 + 16] = sacc;
    __syncthreads();

    float* slot = ws + WS_PART + (ci * NCHUNK + chunk) * PART_STRIDE;
    for (int e = tid; e < 272; e += 256)
        slot[e] = red[0][e] + red[1][e] + red[2][e] + red[3][e];
}

// ---------------------------------------------------------------------------
// Kernel 2: reduce chunk partials (rescaled by 1/DUP_STATS), Newton-Schulz,
// fold WG = W*gamma and C0 = beta - (mean@W)*gamma.
// ---------------------------------------------------------------------------
__global__ __launch_bounds__(256) void k_ns(const float* __restrict__ gamma,
                                            const float* __restrict__ beta,
                                            float* __restrict__ ws) {
    const int ci  = blockIdx.x;
    const int tid = threadIdx.x;
    const int r = tid >> 4, c = tid & 15;
    constexpr float SCL = 1.0f / (float)DUP_STATS;

    __shared__ float red2[272];
    __shared__ float sig[16][17];
    __shared__ float pm[16][17];
    __shared__ float t1[16][17];
    __shared__ float t2[16][17];
    __shared__ float trace_s;

    const float* base = ws + WS_PART + (size_t)ci * NCHUNK * PART_STRIDE;
    for (int e = tid; e < 272; e += 256) {
        float s = 0.0f;
#pragma unroll
        for (int ch = 0; ch < NCHUNK; ++ch)
            s += base[ch * PART_STRIDE + e];
        red2[e] = s * SCL;                      // undo DUP_STATS duplication
    }
    __syncthreads();

    const float P_rc = red2[r * 17 + c];
    const float S_r  = red2[r * 17 + 16];
    const float S_c  = red2[c * 17 + 16];
    sig[r][c] = (P_rc - S_r * S_c * INV_N) * INV_NM1;
    __syncthreads();

    if (tid == 0) {
        float tr = 0.0f;
        for (int i = 0; i < 16; ++i) tr += sig[i][i];
        trace_s = tr;
    }
    __syncthreads();
    const float tr = trace_s;

    sig[r][c] = sig[r][c] / tr;                 // sigma_n
    pm[r][c]  = (r == c) ? 1.0f : 0.0f;
    __syncthreads();

    for (int it = 0; it < 5; ++it) {
        float a = 0.0f;
        for (int k = 0; k < 16; ++k) a += pm[r][k] * pm[k][c];
        t1[r][c] = a;
        __syncthreads();
        float b2 = 0.0f;
        for (int k = 0; k < 16; ++k) b2 += t1[r][k] * pm[k][c];
        t2[r][c] = b2;
        __syncthreads();
        float d = 0.0f;
        for (int k = 0; k < 16; ++k) d += t2[r][k] * sig[k][c];
        const float np = 0.5f * (3.0f * pm[r][c] - d);
        __syncthreads();
        pm[r][c] = np;
        __syncthreads();
    }

    const float inv_sqrt_tr = 1.0f / sqrtf(tr); // W = pm * inv_sqrt_tr
    const float gc = gamma[ci * 16 + c];
    ws[WS_WG + ci * 256 + r * 16 + c] = pm[r][c] * inv_sqrt_tr * gc;
    if (r == 0) {
        float s = 0.0f;
        for (int a = 0; a < 16; ++a) {
            const float mean_a = red2[a * 17 + 16] * INV_N;
            s += mean_a * pm[a][c];
        }
        ws[WS_C0 + ci * 16 + c] = beta[ci * 16 + c] - gc * s * inv_sqrt_tr;
    }
}

// ---------------------------------------------------------------------------
// Kernel 3: out = x @ WG + C0. R10 body exactly, run REP_APPLY times
// (identical idempotent writes) for counter visibility.
// ---------------------------------------------------------------------------
__global__ __launch_bounds__(256) void k_apply(const float* __restrict__ x,
                                               const float* __restrict__ ws,
                                               float* __restrict__ out) {
    const int ci    = blockIdx.x & 31;
    const int chunk = blockIdx.x >> 5;          // 0..31
    const int tid   = threadIdx.x;
    const int sub   = tid & 3;
    const int quad  = tid >> 2;
    const int b0    = sub * 4;

    float wg[16][4];
    const float* WG = ws + WS_WG + ci * 256;
#pragma unroll
    for (int a = 0; a < 16; ++a) {
        const float4 w4 = *reinterpret_cast<const float4*>(WG + a * 16 + b0);
        wg[a][0] = w4.x; wg[a][1] = w4.y; wg[a][2] = w4.z; wg[a][3] = w4.w;
    }
    const float4 c4 = *reinterpret_cast<const float4*>(ws + WS_C0 + ci * 16 + b0);
    const float c0[4] = {c4.x, c4.y, c4.z, c4.w};

    const size_t base =
        (((size_t)(chunk * 64 + (quad >> 5)) * 32 + ci) * 32 + (quad & 31)) * 16;

    auto body = [&](const float4& f0, const float4& f1,
                    const float4& f2, const float4& f3, float* qq) {
        const float v[16] = {f0.x, f0.y, f0.z, f0.w,  f1.x, f1.y, f1.z, f1.w,
                             f2.x, f2.y, f2.z, f2.w,  f3.x, f3.y, f3.z, f3.w};
        float oacc[4] = {c0[0], c0[1], c0[2], c0[3]};
#pragma unroll
        for (int a = 0; a < 16; ++a) {
#pragma unroll
            for (int i = 0; i < 4; ++i) oacc[i] += v[a] * wg[a][i];
        }
        f32x4 o;
        o.x = oacc[0]; o.y = oacc[1]; o.z = oacc[2]; o.w = oacc[3];
        __builtin_nontemporal_store(o, reinterpret_cast<f32x4*>(qq));
    };

    for (int pass = 0; pass < REP_APPLY; ++pass) {
        const float* p = x + base;
        float* q = out + base + b0;

        float4 f0 = *reinterpret_cast<const float4*>(p);
        float4 f1 = *reinterpret_cast<const float4*>(p + 4);
        float4 f2 = *reinterpret_cast<const float4*>(p + 8);
        float4 f3 = *reinterpret_cast<const float4*>(p + 12);

        for (int it = 0; it < 31; ++it) {
            const float* pn = p + 32768;
            const float4 g0 = *reinterpret_cast<const float4*>(pn);
            const float4 g1 = *reinterpret_cast<const float4*>(pn + 4);
            const float4 g2 = *reinterpret_cast<const float4*>(pn + 8);
            const float4 g3 = *reinterpret_cast<const float4*>(pn + 12);

            body(f0, f1, f2, f3, q);

            f0 = g0; f1 = g1; f2 = g2; f3 = g3;
            p = pn; q += 32768;
        }
        body(f0, f1, f2, f3, q);                // peeled last iteration
    }
}

// ---------------------------------------------------------------------------
extern "C" void kernel_launch(void* const* d_in, const int* in_sizes, int n_in,
                              void* d_out, int out_size, void* d_ws, size_t ws_size,
                              hipStream_t stream) {
    const float* x     = (const float*)d_in[0];
    const float* gamma = (const float*)d_in[1];
    const float* beta  = (const float*)d_in[2];
    float* out = (float*)d_out;
    float* ws  = (float*)d_ws;

    k_stats<<<dim3(1024), dim3(256), 0, stream>>>(x, ws);
    k_ns<<<dim3(32), dim3(256), 0, stream>>>(gamma, beta, ws);
    k_apply<<<dim3(1024), dim3(256), 0, stream>>>(x, ws, out);
}

// Round 14
// 78.924 us; speedup vs baseline: 1.8922x; 1.8922x over previous
//
#include <hip/hip_runtime.h>
#include <hip/hip_bf16.h>
#include <math.h>

// Problem constants (reference: B=2048, CI=32, CO=32, A=16, ITER_NUM=5)
constexpr int CI = 32;
constexpr int CO = 32;
constexpr float INV_N   = 1.0f / 65536.0f;
constexpr float INV_NM1 = 1.0f / 65535.0f;

// d_ws float layout (512 MB available; no zero-init required):
//   WS_PART: [CI][256][272] per-(ci,span) partials   (8.9 MB)
//   WS_MID:  [CI][8][272]   octant-reduced partials
//   WS_WG:   [CI][16][16]   folded W*gamma
//   WS_C0:   [CI][16]       folded bias: beta - (mean @ W)*gamma
constexpr int NSPAN = 256;                 // 8-batch spans
constexpr int PART_STRIDE = 272;           // 16 rows * 17 (16 cols + 1 sum)
constexpr int WS_PART = 0;
constexpr int WS_MID  = CI * NSPAN * PART_STRIDE;    // 2228224
constexpr int WS_WG   = WS_MID + CI * 8 * PART_STRIDE;
constexpr int WS_C0   = WS_WG + CI * 256;

using f32x4  = __attribute__((ext_vector_type(4))) float;
using bf16x8 = __attribute__((ext_vector_type(8))) short;

// ---------------------------------------------------------------------------
// Kernel 1 (MFMA Gram, CONTIGUOUS-READ layout): S[a], P[a][b] per capsule.
// Grid: 4 ci-groups * 256 spans = 1024 blocks of 256 threads (4 blocks/CU,
// same occupancy / in-flight bytes / MFMA math as R10 -- the ONLY variable
// changed is the macro address pattern).
// Block (cig, span): 4 waves each own 2 whole batches and compute Grams for
// ALL 8 ci of the group -> a wave reads 16KB CONTIGUOUS per batch (8 adjacent
// ci x 2KB), and the 4 same-span blocks cover each 64KB batch completely.
// (R3/R6/R8/R9/R10/R12 all read 1-2KB islands strided 64-128KB and all
// plateaued at 2.4-3.6 TB/s; sequential readers hit 4.9-7.2 TB/s.)
// 16-step static ping-pong: load fragment for step s+1 while MFMA step s.
// ---------------------------------------------------------------------------
__global__ __launch_bounds__(256) void k_stats(const float* __restrict__ x,
                                               float* __restrict__ ws) {
    const int cig  = blockIdx.x & 3;            // ci group: ci = cig*8 + l
    const int span = blockIdx.x >> 2;           // 0..255, batches span*8..+8
    const int tid  = threadIdx.x;
    const int lane = tid & 63;
    const int wv   = tid >> 6;                  // wave owns batches wv*2+{0,1}
    const int m    = lane & 15;                 // Gram row/col this lane owns
    const int g    = lane >> 4;                 // k-group (co = g*8 + j)

    f32x4 acc[8];                               // one Gram acc per ci_local
    float sacc[8];
#pragma unroll
    for (int l = 0; l < 8; ++l) {
        acc[l] = f32x4{0.0f, 0.0f, 0.0f, 0.0f};
        sacc[l] = 0.0f;
    }

    // Float index of (b, ci, co, a): ((b*32+ci)*32+co)*16 + a.
    // Step s (s>>3 = batch-within-wave bb, s&7 = ci_local l):
    //   offset(s) = bb*16384 + l*512 from pb. Wave stream: l=0..7 covers
    //   16KB contiguous within batch, then +64KB to the next batch.
    const float* pb = x +
        (((size_t)(span * 8 + wv * 2) * 32 + cig * 8) * 32 + g * 8) * 16 + m;

    float bufA[8], bufB[8];
    auto ld = [&](float (&d)[8], const float* q) {
#pragma unroll
        for (int j = 0; j < 8; ++j) d[j] = q[j * 16];
    };
    auto step = [&](float (&buf)[8], int l) {   // l is literal after unroll
        union { bf16x8 v; unsigned short h[8]; } fu;
#pragma unroll
        for (int j = 0; j < 8; ++j) {
            sacc[l] += buf[j];                  // exact fp32 column sum
            fu.h[j] = __bfloat16_as_ushort(__float2bfloat16(buf[j]));
        }
        acc[l] = __builtin_amdgcn_mfma_f32_16x16x32_bf16(fu.v, fu.v, acc[l],
                                                         0, 0, 0);
    };

    ld(bufA, pb);
#pragma unroll
    for (int s = 0; s < 16; ++s) {
        const int nxt = (((s + 1) >> 3) * 16384) + (((s + 1) & 7) * 512);
        if (s < 15) {
            if (s & 1) ld(bufA, pb + nxt); else ld(bufB, pb + nxt);
        }
        if (s & 1) step(bufB, s & 7); else step(bufA, s & 7);
    }

    // S[m] per ci: reduce sacc across the 4 k-groups (lanes 16 apart).
#pragma unroll
    for (int l = 0; l < 8; ++l) {
        sacc[l] += __shfl_xor(sacc[l], 16, 64);
        sacc[l] += __shfl_xor(sacc[l], 32, 64);
    }

    // Cross-wave reduce in LDS (all 4 waves hold the SAME 8 ci's).
    // C/D layout (m89-verified): lane holds P[row=g*4+q][col=m], q=0..3.
    __shared__ float red[4][8 * 272];           // 34.8 KB
#pragma unroll
    for (int l = 0; l < 8; ++l) {
#pragma unroll
        for (int q = 0; q < 4; ++q)
            red[wv][l * 272 + (g * 4 + q) * 17 + m] = acc[l][q];
        if (g == 0) red[wv][l * 272 + m * 17 + 16] = sacc[l];
    }
    __syncthreads();

    for (int e = tid; e < 8 * 272; e += 256) {
        const float ssum = red[0][e] + red[1][e] + red[2][e] + red[3][e];
        const int l = e / 272, k = e - l * 272;
        ws[WS_PART + ((size_t)(cig * 8 + l) * NSPAN + span) * 272 + k] = ssum;
    }
}

// ---------------------------------------------------------------------------
// Kernel 1b: parallel partial reduction 256 spans -> 8 octants per ci.
// 256 blocks so the 8.9 MB reduce runs chip-wide (k_ns alone would be
// 1-CU-per-ci and take ~7us on per-CU BW).
// ---------------------------------------------------------------------------
__global__ __launch_bounds__(256) void k_red(float* __restrict__ ws) {
    const int ci  = blockIdx.x >> 3;
    const int oct = blockIdx.x & 7;
    const int tid = threadIdx.x;

    const float* base =
        ws + WS_PART + ((size_t)ci * NSPAN + oct * 32) * PART_STRIDE;
    for (int e = tid; e < PART_STRIDE; e += 256) {
        float s = 0.0f;
#pragma unroll
        for (int sp = 0; sp < 32; ++sp)
            s += base[sp * PART_STRIDE + e];
        ws[WS_MID + (ci * 8 + oct) * PART_STRIDE + e] = s;
    }
}

// ---------------------------------------------------------------------------
// Kernel 2: reduce 8 octant partials, Newton-Schulz inverse sqrt, then FOLD
// WG = W*gamma and C0 = beta - (mean@W)*gamma. 32 blocks of 256 threads.
// ---------------------------------------------------------------------------
__global__ __launch_bounds__(256) void k_ns(const float* __restrict__ gamma,
                                            const float* __restrict__ beta,
                                            float* __restrict__ ws) {
    const int ci  = blockIdx.x;
    const int tid = threadIdx.x;
    const int r = tid >> 4, c = tid & 15;

    __shared__ float red2[272];
    __shared__ float sig[16][17];
    __shared__ float pm[16][17];
    __shared__ float t1[16][17];
    __shared__ float t2[16][17];
    __shared__ float trace_s;

    const float* base = ws + WS_MID + (size_t)ci * 8 * PART_STRIDE;
    for (int e = tid; e < 272; e += 256) {
        float s = 0.0f;
#pragma unroll
        for (int ch = 0; ch < 8; ++ch)
            s += base[ch * PART_STRIDE + e];
        red2[e] = s;
    }
    __syncthreads();

    // sigma[r][c] = (P_rc - S_r*S_c/N) / (N-1)   (canonical partial layout)
    const float P_rc = red2[r * 17 + c];
    const float S_r  = red2[r * 17 + 16];
    const float S_c  = red2[c * 17 + 16];
    sig[r][c] = (P_rc - S_r * S_c * INV_N) * INV_NM1;
    __syncthreads();

    if (tid == 0) {
        float tr = 0.0f;
        for (int i = 0; i < 16; ++i) tr += sig[i][i];
        trace_s = tr;
    }
    __syncthreads();
    const float tr = trace_s;

    sig[r][c] = sig[r][c] / tr;                 // sigma_n
    pm[r][c]  = (r == c) ? 1.0f : 0.0f;
    __syncthreads();

    for (int it = 0; it < 5; ++it) {
        float a = 0.0f;
        for (int k = 0; k < 16; ++k) a += pm[r][k] * pm[k][c];
        t1[r][c] = a;
        __syncthreads();
        float b2 = 0.0f;
        for (int k = 0; k < 16; ++k) b2 += t1[r][k] * pm[k][c];
        t2[r][c] = b2;
        __syncthreads();
        float d = 0.0f;
        for (int k = 0; k < 16; ++k) d += t2[r][k] * sig[k][c];
        const float np = 0.5f * (3.0f * pm[r][c] - d);
        __syncthreads();
        pm[r][c] = np;
        __syncthreads();
    }

    const float inv_sqrt_tr = 1.0f / sqrtf(tr); // W = pm * inv_sqrt_tr
    const float gc = gamma[ci * 16 + c];
    ws[WS_WG + ci * 256 + r * 16 + c] = pm[r][c] * inv_sqrt_tr * gc;
    if (r == 0) {
        float s = 0.0f;
        for (int a = 0; a < 16; ++a) {
            const float mean_a = red2[a * 17 + 16] * INV_N;
            s += mean_a * pm[a][c];
        }
        ws[WS_C0 + ci * 16 + c] = beta[ci * 16 + c] - gc * s * inv_sqrt_tr;
    }
}

// ---------------------------------------------------------------------------
// Kernel 3: out = x @ WG + C0. EXACT R10 version (its R13 counters show it
// near the mixed write+L3-read floor: 131MB W + 61MB F per pass, 4.4 TB/s).
// ---------------------------------------------------------------------------
__global__ __launch_bounds__(256) void k_apply(const float* __restrict__ x,
                                               const float* __restrict__ ws,
                                               float* __restrict__ out) {
    const int ci    = blockIdx.x & 31;
    const int chunk = blockIdx.x >> 5;          // 0..31
    const int tid   = threadIdx.x;
    const int sub   = tid & 3;
    const int quad  = tid >> 2;
    const int b0    = sub * 4;

    float wg[16][4];
    const float* WG = ws + WS_WG + ci * 256;
#pragma unroll
    for (int a = 0; a < 16; ++a) {
        const float4 w4 = *reinterpret_cast<const float4*>(WG + a * 16 + b0);
        wg[a][0] = w4.x; wg[a][1] = w4.y; wg[a][2] = w4.z; wg[a][3] = w4.w;
    }
    const float4 c4 = *reinterpret_cast<const float4*>(ws + WS_C0 + ci * 16 + b0);
    const float c0[4] = {c4.x, c4.y, c4.z, c4.w};

    const size_t base =
        (((size_t)(chunk * 64 + (quad >> 5)) * 32 + ci) * 32 + (quad & 31)) * 16;
    const float* p = x + base;
    float* q = out + base + b0;

    auto body = [&](const float4& f0, const float4& f1,
                    const float4& f2, const float4& f3, float* qq) {
        const float v[16] = {f0.x, f0.y, f0.z, f0.w,  f1.x, f1.y, f1.z, f1.w,
                             f2.x, f2.y, f2.z, f2.w,  f3.x, f3.y, f3.z, f3.w};
        float oacc[4] = {c0[0], c0[1], c0[2], c0[3]};
#pragma unroll
        for (int a = 0; a < 16; ++a) {
#pragma unroll
            for (int i = 0; i < 4; ++i) oacc[i] += v[a] * wg[a][i];
        }
        f32x4 o;
        o.x = oacc[0]; o.y = oacc[1]; o.z = oacc[2]; o.w = oacc[3];
        __builtin_nontemporal_store(o, reinterpret_cast<f32x4*>(qq));
    };

    float4 f0 = *reinterpret_cast<const float4*>(p);
    float4 f1 = *reinterpret_cast<const float4*>(p + 4);
    float4 f2 = *reinterpret_cast<const float4*>(p + 8);
    float4 f3 = *reinterpret_cast<const float4*>(p + 12);

    for (int it = 0; it < 31; ++it) {
        const float* pn = p + 32768;
        const float4 g0 = *reinterpret_cast<const float4*>(pn);
        const float4 g1 = *reinterpret_cast<const float4*>(pn + 4);
        const float4 g2 = *reinterpret_cast<const float4*>(pn + 8);
        const float4 g3 = *reinterpret_cast<const float4*>(pn + 12);

        body(f0, f1, f2, f3, q);

        f0 = g0; f1 = g1; f2 = g2; f3 = g3;
        p = pn; q += 32768;
    }
    body(f0, f1, f2, f3, q);                    // peeled last iteration
}

// ---------------------------------------------------------------------------
extern "C" void kernel_launch(void* const* d_in, const int* in_sizes, int n_in,
                              void* d_out, int out_size, void* d_ws, size_t ws_size,
                              hipStream_t stream) {
    const float* x     = (const float*)d_in[0];
    const float* gamma = (const float*)d_in[1];
    const float* beta  = (const float*)d_in[2];
    float* out = (float*)d_out;
    float* ws  = (float*)d_ws;

    k_stats<<<dim3(1024), dim3(256), 0, stream>>>(x, ws);
    k_red<<<dim3(256), dim3(256), 0, stream>>>(ws);
    k_ns<<<dim3(32), dim3(256), 0, stream>>>(gamma, beta, ws);
    k_apply<<<dim3(1024), dim3(256), 0, stream>>>(x, ws, out);
}

// Round 15
// 77.923 us; speedup vs baseline: 1.9164x; 1.0128x over previous
//
#include <hip/hip_runtime.h>
#include <hip/hip_bf16.h>
#include <math.h>

// Problem constants (reference: B=2048, CI=32, CO=32, A=16, ITER_NUM=5)
constexpr int CI = 32;
constexpr int CO = 32;
constexpr float INV_N   = 1.0f / 65536.0f;
constexpr float INV_NM1 = 1.0f / 65535.0f;

constexpr int NCHUNK = 32;                 // stats chunks per capsule
constexpr int PART_STRIDE = 272;           // 16 rows * 17 (16 cols + 1 sum)

// d_ws float layout (no zero-init required):
//   WS_PART: [CI][NCHUNK][272] per-block partials, canonical row*17+col
//   WS_WG:   [CI][16][16]  folded W*gamma
//   WS_C0:   [CI][16]      folded bias: beta - (mean @ W)*gamma
constexpr int WS_PART = 0;
constexpr int WS_WG   = CI * NCHUNK * PART_STRIDE;   // 278528
constexpr int WS_C0   = WS_WG + CI * 256;

constexpr int TSTRIDE = 16384;             // floats per batch step (64 KB)
constexpr int LROW    = 18;                // LDS floats per co row (pad 16->18)

using f32x4  = __attribute__((ext_vector_type(4))) float;
using bf16x8 = __attribute__((ext_vector_type(8))) short;

// ---------------------------------------------------------------------------
// Kernel 1 (MFMA Gram, VECTORIZED READS): S[a], P[a][b] per capsule.
// Grid: 32 ci * 32 chunks = 1024 blocks of 256 threads (4 blocks/CU).
// R10's math/layout kept bit-for-bit; ONLY the global access width changes:
//   R10: 8x global_load_dword per 2KB tile (4B/lane; every high-BW kernel on
//        this chip uses 16B/lane -> suspected per-instruction VMEM limit).
//   R15: 2x dense global_load_dwordx4 per tile (lane l -> floats 4l..4l+3),
//        LDS transpose ([co][18] pad: fragment ds_reads are 2-way aliased =
//        free per m136; float2 writes 8B-aligned), wave-private double
//        buffer (in-order DS => no barriers), reg-staged 2-tile prefetch.
// ---------------------------------------------------------------------------
__global__ __launch_bounds__(256) void k_stats(const float* __restrict__ x,
                                               float* __restrict__ ws) {
    const int ci    = blockIdx.x & 31;
    const int chunk = blockIdx.x >> 5;          // 0..31
    const int tid   = threadIdx.x;
    const int lane  = tid & 63;
    const int wv    = tid >> 6;
    const int m     = lane & 15;                // Gram row/col this lane owns
    const int g     = lane >> 4;                // k-group (co = g*8 + j)

    // Wave-private LDS: 2 buffers x 32 co-rows x 18 floats.
    __shared__ float lds[4][2][32 * LROW];      // 18.4 KB
    float* const L0 = lds[wv][0];
    float* const L1 = lds[wv][1];

    // Write slots for this lane's two float4s (co = l>>2 and 16 + l>>2).
    const int wco = lane >> 2;
    const int wa  = (lane & 3) * 4;
    const int w0  = wco * LROW + wa;            // even float offset -> 8B ok
    const int w1  = (16 + wco) * LROW + wa;

    f32x4 acc = {0.0f, 0.0f, 0.0f, 0.0f};
    float sacc = 0.0f;

    // Tile t = batch chunk*64 + wv*16 + t; base float idx ((b*32+ci)*32)*16.
    const float* const pb =
        x + ((size_t)((chunk * 64 + wv * 16) * 32 + ci)) * 512 + lane * 4;

    float4 P0, P1, Q0, Q1;
    auto ldreg = [&](float4& r0, float4& r1, int t) {
        const float* p = pb + (size_t)t * TSTRIDE;
        r0 = *reinterpret_cast<const float4*>(p);        // floats 4l..4l+3
        r1 = *reinterpret_cast<const float4*>(p + 256);  // second 1KB half
    };
    auto wrlds = [&](float* buf, const float4& r0, const float4& r1) {
        *reinterpret_cast<float2*>(buf + w0)     = float2{r0.x, r0.y};
        *reinterpret_cast<float2*>(buf + w0 + 2) = float2{r0.z, r0.w};
        *reinterpret_cast<float2*>(buf + w1)     = float2{r1.x, r1.y};
        *reinterpret_cast<float2*>(buf + w1 + 2) = float2{r1.z, r1.w};
    };
    auto proc = [&](const float* buf) {
        const float* rp = buf + m;              // + (g*8+j)*LROW per j
        union { bf16x8 v; unsigned short h[8]; } fu;
#pragma unroll
        for (int j = 0; j < 8; ++j) {
            const float val = rp[(g * 8 + j) * LROW];
            sacc += val;                        // exact fp32 column sum
            fu.h[j] = __bfloat16_as_ushort(__float2bfloat16(val));
        }
        acc = __builtin_amdgcn_mfma_f32_16x16x32_bf16(fu.v, fu.v, acc, 0, 0, 0);
    };

    // Prologue: tile0 -> L0; tile1 -> P; tile2 -> Q.
    ldreg(P0, P1, 0);
    wrlds(L0, P0, P1);
    ldreg(P0, P1, 1);
    ldreg(Q0, Q1, 2);

#pragma unroll
    for (int pr = 0; pr < 8; ++pr) {            // tiles (2pr, 2pr+1)
        wrlds(L1, P0, P1);                      // stage tile 2pr+1
        proc(L0);                               // consume tile 2pr
        if (pr < 7) ldreg(P0, P1, 2 * pr + 3);
        if (pr < 7) wrlds(L0, Q0, Q1);          // stage tile 2pr+2
        proc(L1);                               // consume tile 2pr+1
        if (pr < 6) ldreg(Q0, Q1, 2 * pr + 4);
    }

    // S[m]: sum sacc across the 4 k-groups (lanes 16 apart).
    sacc += __shfl_xor(sacc, 16, 64);
    sacc += __shfl_xor(sacc, 32, 64);

    // C/D layout (m89-verified): lane holds P[row=g*4+q][col=m], q=0..3.
    __shared__ float red[4][272];
#pragma unroll
    for (int q = 0; q < 4; ++q)
        red[wv][(g * 4 + q) * 17 + m] = acc[q];
    if (g == 0) red[wv][m * 17 + 16] = sacc;
    __syncthreads();

    float* slot = ws + WS_PART + (ci * NCHUNK + chunk) * PART_STRIDE;
    for (int e = tid; e < 272; e += 256)
        slot[e] = red[0][e] + red[1][e] + red[2][e] + red[3][e];
}

// ---------------------------------------------------------------------------
// Kernel 2: reduce chunk partials, Newton-Schulz inverse sqrt, then FOLD the
// epilogue constants: WG = W*gamma (per column), C0 = beta - (mean@W)*gamma.
// 32 blocks (one per ci) of 256 threads. (Unchanged from R10.)
// ---------------------------------------------------------------------------
__global__ __launch_bounds__(256) void k_ns(const float* __restrict__ gamma,
                                            const float* __restrict__ beta,
                                            float* __restrict__ ws) {
    const int ci  = blockIdx.x;
    const int tid = threadIdx.x;
    const int r = tid >> 4, c = tid & 15;

    __shared__ float red2[272];
    __shared__ float sig[16][17];
    __shared__ float pm[16][17];
    __shared__ float t1[16][17];
    __shared__ float t2[16][17];
    __shared__ float trace_s;

    const float* base = ws + WS_PART + (size_t)ci * NCHUNK * PART_STRIDE;
    for (int e = tid; e < 272; e += 256) {
        float s = 0.0f;
#pragma unroll
        for (int ch = 0; ch < NCHUNK; ++ch)
            s += base[ch * PART_STRIDE + e];
        red2[e] = s;
    }
    __syncthreads();

    // sigma[r][c] = (P_rc - S_r*S_c/N) / (N-1)   (canonical partial layout)
    const float P_rc = red2[r * 17 + c];
    const float S_r  = red2[r * 17 + 16];
    const float S_c  = red2[c * 17 + 16];
    sig[r][c] = (P_rc - S_r * S_c * INV_N) * INV_NM1;
    __syncthreads();

    if (tid == 0) {
        float tr = 0.0f;
        for (int i = 0; i < 16; ++i) tr += sig[i][i];
        trace_s = tr;
    }
    __syncthreads();
    const float tr = trace_s;

    sig[r][c] = sig[r][c] / tr;                 // sigma_n
    pm[r][c]  = (r == c) ? 1.0f : 0.0f;
    __syncthreads();

    for (int it = 0; it < 5; ++it) {
        float a = 0.0f;
        for (int k = 0; k < 16; ++k) a += pm[r][k] * pm[k][c];
        t1[r][c] = a;
        __syncthreads();
        float b2 = 0.0f;
        for (int k = 0; k < 16; ++k) b2 += t1[r][k] * pm[k][c];
        t2[r][c] = b2;
        __syncthreads();
        float d = 0.0f;
        for (int k = 0; k < 16; ++k) d += t2[r][k] * sig[k][c];
        const float np = 0.5f * (3.0f * pm[r][c] - d);
        __syncthreads();
        pm[r][c] = np;
        __syncthreads();
    }

    const float inv_sqrt_tr = 1.0f / sqrtf(tr); // W = pm * inv_sqrt_tr
    const float gc = gamma[ci * 16 + c];
    ws[WS_WG + ci * 256 + r * 16 + c] = pm[r][c] * inv_sqrt_tr * gc;
    if (r == 0) {
        float s = 0.0f;
        for (int a = 0; a < 16; ++a) {
            const float mean_a = red2[a * 17 + 16] * INV_N;
            s += mean_a * pm[a][c];
        }
        ws[WS_C0 + ci * 16 + c] = beta[ci * 16 + c] - gc * s * inv_sqrt_tr;
    }
}

// ---------------------------------------------------------------------------
// Kernel 3: out = x @ WG + C0. EXACT R10 version (R13 counters: near the
// mixed write+L3-read floor).
// ---------------------------------------------------------------------------
__global__ __launch_bounds__(256) void k_apply(const float* __restrict__ x,
                                               const float* __restrict__ ws,
                                               float* __restrict__ out) {
    const int ci    = blockIdx.x & 31;
    const int chunk = blockIdx.x >> 5;          // 0..31
    const int tid   = threadIdx.x;
    const int sub   = tid & 3;
    const int quad  = tid >> 2;
    const int b0    = sub * 4;

    float wg[16][4];
    const float* WG = ws + WS_WG + ci * 256;
#pragma unroll
    for (int a = 0; a < 16; ++a) {
        const float4 w4 = *reinterpret_cast<const float4*>(WG + a * 16 + b0);
        wg[a][0] = w4.x; wg[a][1] = w4.y; wg[a][2] = w4.z; wg[a][3] = w4.w;
    }
    const float4 c4 = *reinterpret_cast<const float4*>(ws + WS_C0 + ci * 16 + b0);
    const float c0[4] = {c4.x, c4.y, c4.z, c4.w};

    const size_t base =
        (((size_t)(chunk * 64 + (quad >> 5)) * 32 + ci) * 32 + (quad & 31)) * 16;
    const float* p = x + base;
    float* q = out + base + b0;

    auto body = [&](const float4& f0, const float4& f1,
                    const float4& f2, const float4& f3, float* qq) {
        const float v[16] = {f0.x, f0.y, f0.z, f0.w,  f1.x, f1.y, f1.z, f1.w,
                             f2.x, f2.y, f2.z, f2.w,  f3.x, f3.y, f3.z, f3.w};
        float oacc[4] = {c0[0], c0[1], c0[2], c0[3]};
#pragma unroll
        for (int a = 0; a < 16; ++a) {
#pragma unroll
            for (int i = 0; i < 4; ++i) oacc[i] += v[a] * wg[a][i];
        }
        f32x4 o;
        o.x = oacc[0]; o.y = oacc[1]; o.z = oacc[2]; o.w = oacc[3];
        __builtin_nontemporal_store(o, reinterpret_cast<f32x4*>(qq));
    };

    float4 f0 = *reinterpret_cast<const float4*>(p);
    float4 f1 = *reinterpret_cast<const float4*>(p + 4);
    float4 f2 = *reinterpret_cast<const float4*>(p + 8);
    float4 f3 = *reinterpret_cast<const float4*>(p + 12);

    for (int it = 0; it < 31; ++it) {
        const float* pn = p + 32768;
        const float4 g0 = *reinterpret_cast<const float4*>(pn);
        const float4 g1 = *reinterpret_cast<const float4*>(pn + 4);
        const float4 g2 = *reinterpret_cast<const float4*>(pn + 8);
        const float4 g3 = *reinterpret_cast<const float4*>(pn + 12);

        body(f0, f1, f2, f3, q);

        f0 = g0; f1 = g1; f2 = g2; f3 = g3;
        p = pn; q += 32768;
    }
    body(f0, f1, f2, f3, q);                    // peeled last iteration
}

// ---------------------------------------------------------------------------
extern "C" void kernel_launch(void* const* d_in, const int* in_sizes, int n_in,
                              void* d_out, int out_size, void* d_ws, size_t ws_size,
                              hipStream_t stream) {
    const float* x     = (const float*)d_in[0];
    const float* gamma = (const float*)d_in[1];
    const float* beta  = (const float*)d_in[2];
    float* out = (float*)d_out;
    float* ws  = (float*)d_ws;

    k_stats<<<dim3(1024), dim3(256), 0, stream>>>(x, ws);
    k_ns<<<dim3(32), dim3(256), 0, stream>>>(gamma, beta, ws);
    k_apply<<<dim3(1024), dim3(256), 0, stream>>>(x, ws, out);
}

// Round 16
// 77.729 us; speedup vs baseline: 1.9212x; 1.0025x over previous
//
#include <hip/hip_runtime.h>
#include <hip/hip_bf16.h>
#include <math.h>

// Problem constants (reference: B=2048, CI=32, CO=32, A=16, ITER_NUM=5)
constexpr int CI = 32;
constexpr int CO = 32;
constexpr float INV_N   = 1.0f / 65536.0f;
constexpr float INV_NM1 = 1.0f / 65535.0f;

constexpr int NCHUNK = 32;                 // stats chunks per capsule
constexpr int PART_STRIDE = 272;           // 16 rows * 17 (16 cols + 1 sum)

// d_ws float layout (no zero-init required):
//   WS_PART: [CI][NCHUNK][272] per-block partials, canonical row*17+col
//   WS_WG:   [CI][16][16]  folded W*gamma
//   WS_C0:   [CI][16]      folded bias: beta - (mean @ W)*gamma
constexpr int WS_PART = 0;
constexpr int WS_WG   = CI * NCHUNK * PART_STRIDE;   // 278528
constexpr int WS_C0   = WS_WG + CI * 256;

constexpr int TSTRIDE = 16384;             // floats per batch step (64 KB)

using f32x4  = __attribute__((ext_vector_type(4))) float;
using bf16x8 = __attribute__((ext_vector_type(8))) short;

// Async global->LDS DMA, 16B per lane: LDS dest = uniform base + lane*16,
// global src = per-lane pointer. No VGPR destination -> the load leaves the
// wave's register dependency chain entirely (synced via counted vmcnt).
__device__ __forceinline__ void dma16(const float* g, float* l) {
    __builtin_amdgcn_global_load_lds(
        (const __attribute__((address_space(1))) void*)g,
        (__attribute__((address_space(3))) void*)l,
        16, 0, 0);
}

template <int N>
__device__ __forceinline__ void wait_vm() {
    asm volatile("s_waitcnt vmcnt(%0)" :: "n"(N) : "memory");
}

// ---------------------------------------------------------------------------
// Kernel 1 (MFMA Gram + global_load_lds): S[a], P[a][b] per capsule.
// Grid: 32 ci * 32 chunks = 1024 blocks of 256 threads (4 blocks/CU, LDS-
// bound: 36.3KB/block).
// Per 2KB tile (one batch's 32 vectors of this ci): 2 dense width-16
// global_load_lds (lane l -> bytes l*16, linear LDS [co][16]). 4-deep tile
// pipeline per wave with counted vmcnt(6) waits -- loads stay in flight
// across compute, never drained to 0 (T3/T4). Every previous variant kept
// loads in the VGPR dependency chain and plateaued at 2.4-3.6 TB/s.
// Fragment ds_reads use g-rotated k-order co = g*8+((j+g)&7): bank parity
// alternates -> 2-way conflict (free, m136); the same permutation feeds the
// A and B fragments so it cancels in the Gram k-sum.
// ---------------------------------------------------------------------------
__global__ __launch_bounds__(256) void k_stats(const float* __restrict__ x,
                                               float* __restrict__ ws) {
    const int ci    = blockIdx.x & 31;
    const int chunk = blockIdx.x >> 5;          // 0..31
    const int tid   = threadIdx.x;
    const int lane  = tid & 63;
    const int wv    = tid >> 6;
    const int m     = lane & 15;                // Gram row/col this lane owns
    const int g     = lane >> 4;                // k-group (co = g*8 + j)

    __shared__ float tiles[4][4][512];          // 4 waves x 4-deep x 2KB
    __shared__ float red[4][272];

    f32x4 acc = {0.0f, 0.0f, 0.0f, 0.0f};
    float sacc = 0.0f;

    // Tile t = batch chunk*64 + wv*16 + t. Per-lane global src for the two
    // 1KB halves: gbase + t*16384 (+256).
    const float* const gbase =
        x + ((size_t)((chunk * 64 + wv * 16) * 32 + ci)) * 512 + lane * 4;

    auto issue2 = [&](int t) {
        float* lbuf = &tiles[wv][t & 3][0];
        const float* gp = gbase + (size_t)t * TSTRIDE;
        dma16(gp, lbuf);
        dma16(gp + 256, lbuf + 256);
    };
    auto proc = [&](int slot) {
        const float* rp = &tiles[wv][slot][g * 128 + m];
        union { bf16x8 v; unsigned short h[8]; } fu;
#pragma unroll
        for (int j = 0; j < 8; ++j) {
            const float val = rp[((j + g) & 7) * 16];   // rotated k-order
            sacc += val;                                // exact fp32 col sum
            fu.h[j] = __bfloat16_as_ushort(__float2bfloat16(val));
        }
        acc = __builtin_amdgcn_mfma_f32_16x16x32_bf16(fu.v, fu.v, acc, 0, 0, 0);
    };

    // Prologue: fill the 4-deep pipe (8 DMA ops outstanding).
    issue2(0); issue2(1); issue2(2); issue2(3);

    for (int t = 0; t < 13; ++t) {
        wait_vm<6>();                           // oldest tile landed
        __builtin_amdgcn_sched_barrier(0);      // rule #18: pin consume
        proc(t & 3);
        asm volatile("" ::: "memory");          // reads precede slot reuse
        if (t < 12) issue2(t + 4);
    }
    wait_vm<4>(); proc(1);                      // tiles 13,14,15
    wait_vm<2>(); proc(2);
    wait_vm<0>(); proc(3);

    // S[m]: sum sacc across the 4 k-groups (lanes 16 apart).
    sacc += __shfl_xor(sacc, 16, 64);
    sacc += __shfl_xor(sacc, 32, 64);

    // C/D layout (m89-verified): lane holds P[row=g*4+q][col=m], q=0..3.
#pragma unroll
    for (int q = 0; q < 4; ++q)
        red[wv][(g * 4 + q) * 17 + m] = acc[q];
    if (g == 0) red[wv][m * 17 + 16] = sacc;
    __syncthreads();

    float* slot = ws + WS_PART + (ci * NCHUNK + chunk) * PART_STRIDE;
    for (int e = tid; e < 272; e += 256)
        slot[e] = red[0][e] + red[1][e] + red[2][e] + red[3][e];
}

// ---------------------------------------------------------------------------
// Kernel 2: reduce chunk partials, Newton-Schulz inverse sqrt, then FOLD the
// epilogue constants: WG = W*gamma (per column), C0 = beta - (mean@W)*gamma.
// 32 blocks (one per ci) of 256 threads. (Unchanged from R10.)
// ---------------------------------------------------------------------------
__global__ __launch_bounds__(256) void k_ns(const float* __restrict__ gamma,
                                            const float* __restrict__ beta,
                                            float* __restrict__ ws) {
    const int ci  = blockIdx.x;
    const int tid = threadIdx.x;
    const int r = tid >> 4, c = tid & 15;

    __shared__ float red2[272];
    __shared__ float sig[16][17];
    __shared__ float pm[16][17];
    __shared__ float t1[16][17];
    __shared__ float t2[16][17];
    __shared__ float trace_s;

    const float* base = ws + WS_PART + (size_t)ci * NCHUNK * PART_STRIDE;
    for (int e = tid; e < 272; e += 256) {
        float s = 0.0f;
#pragma unroll
        for (int ch = 0; ch < NCHUNK; ++ch)
            s += base[ch * PART_STRIDE + e];
        red2[e] = s;
    }
    __syncthreads();

    // sigma[r][c] = (P_rc - S_r*S_c/N) / (N-1)   (canonical partial layout)
    const float P_rc = red2[r * 17 + c];
    const float S_r  = red2[r * 17 + 16];
    const float S_c  = red2[c * 17 + 16];
    sig[r][c] = (P_rc - S_r * S_c * INV_N) * INV_NM1;
    __syncthreads();

    if (tid == 0) {
        float tr = 0.0f;
        for (int i = 0; i < 16; ++i) tr += sig[i][i];
        trace_s = tr;
    }
    __syncthreads();
    const float tr = trace_s;

    sig[r][c] = sig[r][c] / tr;                 // sigma_n
    pm[r][c]  = (r == c) ? 1.0f : 0.0f;
    __syncthreads();

    for (int it = 0; it < 5; ++it) {
        float a = 0.0f;
        for (int k = 0; k < 16; ++k) a += pm[r][k] * pm[k][c];
        t1[r][c] = a;
        __syncthreads();
        float b2 = 0.0f;
        for (int k = 0; k < 16; ++k) b2 += t1[r][k] * pm[k][c];
        t2[r][c] = b2;
        __syncthreads();
        float d = 0.0f;
        for (int k = 0; k < 16; ++k) d += t2[r][k] * sig[k][c];
        const float np = 0.5f * (3.0f * pm[r][c] - d);
        __syncthreads();
        pm[r][c] = np;
        __syncthreads();
    }

    const float inv_sqrt_tr = 1.0f / sqrtf(tr); // W = pm * inv_sqrt_tr
    const float gc = gamma[ci * 16 + c];
    ws[WS_WG + ci * 256 + r * 16 + c] = pm[r][c] * inv_sqrt_tr * gc;
    if (r == 0) {
        float s = 0.0f;
        for (int a = 0; a < 16; ++a) {
            const float mean_a = red2[a * 17 + 16] * INV_N;
            s += mean_a * pm[a][c];
        }
        ws[WS_C0 + ci * 16 + c] = beta[ci * 16 + c] - gc * s * inv_sqrt_tr;
    }
}

// ---------------------------------------------------------------------------
// Kernel 3: out = x @ WG + C0. EXACT R10 version (R13 counters: near the
// mixed write+L3-read floor: 131MB W + 61MB F per pass).
// ---------------------------------------------------------------------------
__global__ __launch_bounds__(256) void k_apply(const float* __restrict__ x,
                                               const float* __restrict__ ws,
                                               float* __restrict__ out) {
    const int ci    = blockIdx.x & 31;
    const int chunk = blockIdx.x >> 5;          // 0..31
    const int tid   = threadIdx.x;
    const int sub   = tid & 3;
    const int quad  = tid >> 2;
    const int b0    = sub * 4;

    float wg[16][4];
    const float* WG = ws + WS_WG + ci * 256;
#pragma unroll
    for (int a = 0; a < 16; ++a) {
        const float4 w4 = *reinterpret_cast<const float4*>(WG + a * 16 + b0);
        wg[a][0] = w4.x; wg[a][1] = w4.y; wg[a][2] = w4.z; wg[a][3] = w4.w;
    }
    const float4 c4 = *reinterpret_cast<const float4*>(ws + WS_C0 + ci * 16 + b0);
    const float c0[4] = {c4.x, c4.y, c4.z, c4.w};

    const size_t base =
        (((size_t)(chunk * 64 + (quad >> 5)) * 32 + ci) * 32 + (quad & 31)) * 16;
    const float* p = x + base;
    float* q = out + base + b0;

    auto body = [&](const float4& f0, const float4& f1,
                    const float4& f2, const float4& f3, float* qq) {
        const float v[16] = {f0.x, f0.y, f0.z, f0.w,  f1.x, f1.y, f1.z, f1.w,
                             f2.x, f2.y, f2.z, f2.w,  f3.x, f3.y, f3.z, f3.w};
        float oacc[4] = {c0[0], c0[1], c0[2], c0[3]};
#pragma unroll
        for (int a = 0; a < 16; ++a) {
#pragma unroll
            for (int i = 0; i < 4; ++i) oacc[i] += v[a] * wg[a][i];
        }
        f32x4 o;
        o.x = oacc[0]; o.y = oacc[1]; o.z = oacc[2]; o.w = oacc[3];
        __builtin_nontemporal_store(o, reinterpret_cast<f32x4*>(qq));
    };

    float4 f0 = *reinterpret_cast<const float4*>(p);
    float4 f1 = *reinterpret_cast<const float4*>(p + 4);
    float4 f2 = *reinterpret_cast<const float4*>(p + 8);
    float4 f3 = *reinterpret_cast<const float4*>(p + 12);

    for (int it = 0; it < 31; ++it) {
        const float* pn = p + 32768;
        const float4 g0 = *reinterpret_cast<const float4*>(pn);
        const float4 g1 = *reinterpret_cast<const float4*>(pn + 4);
        const float4 g2 = *reinterpret_cast<const float4*>(pn + 8);
        const float4 g3 = *reinterpret_cast<const float4*>(pn + 12);

        body(f0, f1, f2, f3, q);

        f0 = g0; f1 = g1; f2 = g2; f3 = g3;
        p = pn; q += 32768;
    }
    body(f0, f1, f2, f3, q);                    // peeled last iteration
}

// ---------------------------------------------------------------------------
extern "C" void kernel_launch(void* const* d_in, const int* in_sizes, int n_in,
                              void* d_out, int out_size, void* d_ws, size_t ws_size,
                              hipStream_t stream) {
    const float* x     = (const float*)d_in[0];
    const float* gamma = (const float*)d_in[1];
    const float* beta  = (const float*)d_in[2];
    float* out = (float*)d_out;
    float* ws  = (float*)d_ws;

    k_stats<<<dim3(1024), dim3(256), 0, stream>>>(x, ws);
    k_ns<<<dim3(32), dim3(256), 0, stream>>>(gamma, beta, ws);
    k_apply<<<dim3(1024), dim3(256), 0, stream>>>(x, ws, out);
}

// Round 17
// 76.492 us; speedup vs baseline: 1.9523x; 1.0162x over previous
//
#include <hip/hip_runtime.h>
#include <hip/hip_bf16.h>
#include <math.h>

// Problem constants (reference: B=2048, CI=32, CO=32, A=16, ITER_NUM=5)
constexpr int CI = 32;
constexpr int CO = 32;
constexpr float INV_N   = 1.0f / 65536.0f;
constexpr float INV_NM1 = 1.0f / 65535.0f;

// DIAGNOSTIC: k_stats runs its (unchanged R10) pass 3x so it rises above the
// ~75us harness poison-fills and exposes counters. x fits in L3 (134<256MB),
// so passes 2-3 are L3-fed: if stats is HBM-source-bound they run FASTER
// (k_stats(x3) ~ 80-100us, FETCH << 402MB); if internally bound they don't
// (~110us+, FETCH/VALUBusy name the pipe). k_ns rescales by exactly 1/3.
constexpr int DUP_STATS = 3;

constexpr int NCHUNK = 32;                 // stats chunks per capsule
constexpr int PART_STRIDE = 272;           // 16 rows * 17 (16 cols + 1 sum)

constexpr int WS_PART = 0;
constexpr int WS_WG   = CI * NCHUNK * PART_STRIDE;   // 278528
constexpr int WS_C0   = WS_WG + CI * 256;

constexpr int BSTRIDE = 16384;             // floats per batch (64 KB)

using f32x4  = __attribute__((ext_vector_type(4))) float;
using bf16x8 = __attribute__((ext_vector_type(8))) short;

// ---------------------------------------------------------------------------
// Kernel 1 (MFMA Gram): R10 body exactly, wrapped in DUP_STATS passes.
// Grid: 32 ci * 32 chunks = 1024 blocks of 256 threads (4 blocks/CU).
// ---------------------------------------------------------------------------
__global__ __launch_bounds__(256) void k_stats(const float* __restrict__ x,
                                               float* __restrict__ ws) {
    const int ci    = blockIdx.x & 31;
    const int chunk = blockIdx.x >> 5;          // 0..31
    const int tid   = threadIdx.x;
    const int lane  = tid & 63;
    const int wv    = tid >> 6;
    const int m     = lane & 15;                // row/col index this lane owns
    const int g     = lane >> 4;                // k-group (co = g*8 + j)

    f32x4 acc = {0.0f, 0.0f, 0.0f, 0.0f};
    float sacc = 0.0f;

    const int b0 = chunk * 64 + wv * 16;
    const float* const pbase =
        x + ((size_t)(b0 * 32 + ci) * 32 + g * 8) * 16 + m;

    float bufA[8], bufB[8];

    auto ld = [&](float (&d)[8], const float* q) {
#pragma unroll
        for (int j = 0; j < 8; ++j) d[j] = q[j * 16];
    };
    auto step = [&](float (&buf)[8]) {
        union { bf16x8 v; unsigned short h[8]; } fu;
#pragma unroll
        for (int j = 0; j < 8; ++j) {
            sacc += buf[j];                     // exact fp32 column sum
            fu.h[j] = __bfloat16_as_ushort(__float2bfloat16(buf[j]));
        }
        acc = __builtin_amdgcn_mfma_f32_16x16x32_bf16(fu.v, fu.v, acc, 0, 0, 0);
    };

    for (int pass = 0; pass < DUP_STATS; ++pass) {
        const float* p = pbase;
        ld(bufA, p);
        ld(bufB, p + BSTRIDE);
        p += 2 * BSTRIDE;
#pragma unroll
        for (int rr = 0; rr < 8; ++rr) {
            step(bufA);
            if (rr < 7) { ld(bufA, p); p += BSTRIDE; }
            step(bufB);
            if (rr < 7) { ld(bufB, p); p += BSTRIDE; }
        }
    }

    // S[m]: sum sacc across the 4 k-groups (lanes 16 apart).
    sacc += __shfl_xor(sacc, 16, 64);
    sacc += __shfl_xor(sacc, 32, 64);

    // C/D layout (m89-verified): lane holds P[row=g*4+q][col=m], q=0..3.
    __shared__ float red[4][272];
#pragma unroll
    for (int q = 0; q < 4; ++q)
        red[wv][(g * 4 + q) * 17 + m] = acc[q];
    if (g == 0) red[wv][m * 17 + 16] = sacc;
    __syncthreads();

    float* slot = ws + WS_PART + (ci * NCHUNK + chunk) * PART_STRIDE;
    for (int e = tid; e < 272; e += 256)
        slot[e] = red[0][e] + red[1][e] + red[2][e] + red[3][e];
}

// ---------------------------------------------------------------------------
// Kernel 2: reduce chunk partials (rescaled by 1/DUP_STATS), Newton-Schulz,
// fold WG = W*gamma and C0 = beta - (mean@W)*gamma. (R10 + SCL.)
// ---------------------------------------------------------------------------
__global__ __launch_bounds__(256) void k_ns(const float* __restrict__ gamma,
                                            const float* __restrict__ beta,
                                            float* __restrict__ ws) {
    const int ci  = blockIdx.x;
    const int tid = threadIdx.x;
    const int r = tid >> 4, c = tid & 15;
    constexpr float SCL = 1.0f / (float)DUP_STATS;

    __shared__ float red2[272];
    __shared__ float sig[16][17];
    __shared__ float pm[16][17];
    __shared__ float t1[16][17];
    __shared__ float t2[16][17];
    __shared__ float trace_s;

    const float* base = ws + WS_PART + (size_t)ci * NCHUNK * PART_STRIDE;
    for (int e = tid; e < 272; e += 256) {
        float s = 0.0f;
#pragma unroll
        for (int ch = 0; ch < NCHUNK; ++ch)
            s += base[ch * PART_STRIDE + e];
        red2[e] = s * SCL;                      // undo DUP_STATS duplication
    }
    __syncthreads();

    // sigma[r][c] = (P_rc - S_r*S_c/N) / (N-1)   (canonical partial layout)
    const float P_rc = red2[r * 17 + c];
    const float S_r  = red2[r * 17 + 16];
    const float S_c  = red2[c * 17 + 16];
    sig[r][c] = (P_rc - S_r * S_c * INV_N) * INV_NM1;
    __syncthreads();

    if (tid == 0) {
        float tr = 0.0f;
        for (int i = 0; i < 16; ++i) tr += sig[i][i];
        trace_s = tr;
    }
    __syncthreads();
    const float tr = trace_s;

    sig[r][c] = sig[r][c] / tr;                 // sigma_n
    pm[r][c]  = (r == c) ? 1.0f : 0.0f;
    __syncthreads();

    for (int it = 0; it < 5; ++it) {
        float a = 0.0f;
        for (int k = 0; k < 16; ++k) a += pm[r][k] * pm[k][c];
        t1[r][c] = a;
        __syncthreads();
        float b2 = 0.0f;
        for (int k = 0; k < 16; ++k) b2 += t1[r][k] * pm[k][c];
        t2[r][c] = b2;
        __syncthreads();
        float d = 0.0f;
        for (int k = 0; k < 16; ++k) d += t2[r][k] * sig[k][c];
        const float np = 0.5f * (3.0f * pm[r][c] - d);
        __syncthreads();
        pm[r][c] = np;
        __syncthreads();
    }

    const float inv_sqrt_tr = 1.0f / sqrtf(tr); // W = pm * inv_sqrt_tr
    const float gc = gamma[ci * 16 + c];
    ws[WS_WG + ci * 256 + r * 16 + c] = pm[r][c] * inv_sqrt_tr * gc;
    if (r == 0) {
        float s = 0.0f;
        for (int a = 0; a < 16; ++a) {
            const float mean_a = red2[a * 17 + 16] * INV_N;
            s += mean_a * pm[a][c];
        }
        ws[WS_C0 + ci * 16 + c] = beta[ci * 16 + c] - gc * s * inv_sqrt_tr;
    }
}

// ---------------------------------------------------------------------------
// Kernel 3: out = x @ WG + C0. EXACT R10 version.
// ---------------------------------------------------------------------------
__global__ __launch_bounds__(256) void k_apply(const float* __restrict__ x,
                                               const float* __restrict__ ws,
                                               float* __restrict__ out) {
    const int ci    = blockIdx.x & 31;
    const int chunk = blockIdx.x >> 5;          // 0..31
    const int tid   = threadIdx.x;
    const int sub   = tid & 3;
    const int quad  = tid >> 2;
    const int b0    = sub * 4;

    float wg[16][4];
    const float* WG = ws + WS_WG + ci * 256;
#pragma unroll
    for (int a = 0; a < 16; ++a) {
        const float4 w4 = *reinterpret_cast<const float4*>(WG + a * 16 + b0);
        wg[a][0] = w4.x; wg[a][1] = w4.y; wg[a][2] = w4.z; wg[a][3] = w4.w;
    }
    const float4 c4 = *reinterpret_cast<const float4*>(ws + WS_C0 + ci * 16 + b0);
    const float c0[4] = {c4.x, c4.y, c4.z, c4.w};

    const size_t base =
        (((size_t)(chunk * 64 + (quad >> 5)) * 32 + ci) * 32 + (quad & 31)) * 16;
    const float* p = x + base;
    float* q = out + base + b0;

    auto body = [&](const float4& f0, const float4& f1,
                    const float4& f2, const float4& f3, float* qq) {
        const float v[16] = {f0.x, f0.y, f0.z, f0.w,  f1.x, f1.y, f1.z, f1.w,
                             f2.x, f2.y, f2.z, f2.w,  f3.x, f3.y, f3.z, f3.w};
        float oacc[4] = {c0[0], c0[1], c0[2], c0[3]};
#pragma unroll
        for (int a = 0; a < 16; ++a) {
#pragma unroll
            for (int i = 0; i < 4; ++i) oacc[i] += v[a] * wg[a][i];
        }
        f32x4 o;
        o.x = oacc[0]; o.y = oacc[1]; o.z = oacc[2]; o.w = oacc[3];
        __builtin_nontemporal_store(o, reinterpret_cast<f32x4*>(qq));
    };

    float4 f0 = *reinterpret_cast<const float4*>(p);
    float4 f1 = *reinterpret_cast<const float4*>(p + 4);
    float4 f2 = *reinterpret_cast<const float4*>(p + 8);
    float4 f3 = *reinterpret_cast<const float4*>(p + 12);

    for (int it = 0; it < 31; ++it) {
        const float* pn = p + 32768;
        const float4 g0 = *reinterpret_cast<const float4*>(pn);
        const float4 g1 = *reinterpret_cast<const float4*>(pn + 4);
        const float4 g2 = *reinterpret_cast<const float4*>(pn + 8);
        const float4 g3 = *reinterpret_cast<const float4*>(pn + 12);

        body(f0, f1, f2, f3, q);

        f0 = g0; f1 = g1; f2 = g2; f3 = g3;
        p = pn; q += 32768;
    }
    body(f0, f1, f2, f3, q);                    // peeled last iteration
}

// ---------------------------------------------------------------------------
extern "C" void kernel_launch(void* const* d_in, const int* in_sizes, int n_in,
                              void* d_out, int out_size, void* d_ws, size_t ws_size,
                              hipStream_t stream) {
    const float* x     = (const float*)d_in[0];
    const float* gamma = (const float*)d_in[1];
    const float* beta  = (const float*)d_in[2];
    float* out = (float*)d_out;
    float* ws  = (float*)d_ws;

    k_stats<<<dim3(1024), dim3(256), 0, stream>>>(x, ws);
    k_ns<<<dim3(32), dim3(256), 0, stream>>>(gamma, beta, ws);
    k_apply<<<dim3(1024), dim3(256), 0, stream>>>(x, ws, out);
}